// Round 1
// baseline (304.551 us; speedup 1.0000x reference)
//
#include <hip/hip_runtime.h>
#include <math.h>

// Problem constants: B=32 batches, N=64 points, D=64 hidden.
#define BB 32
#define NN 64
#define DD 64
// Each precomputed attention matrix: B*N*N floats.
constexpr int MAT = BB * NN * NN; // 131072 floats

// ---------------------------------------------------------------------------
// Phase 1: precompute the six (B,N,N) attention matrices, pre-scaled by
// -scale*log2(e) so the main loop's sigmoid is rcp(1+exp2(sum)).
// Key insight: q_i . k_j = aug(p_i)^T (Wq_aug Wk_aug^T) aug(p_j), a 4x4 form.
// Also zeroes the pooled accumulator (ws is poisoned before every launch).
// ---------------------------------------------------------------------------
__global__ __launch_bounds__(256) void simplex_phase1(
    const float* __restrict__ pc,
    const float* __restrict__ Wq,  const float* __restrict__ bq,
    const float* __restrict__ Wk1, const float* __restrict__ bk1,
    const float* __restrict__ Wk2, const float* __restrict__ bk2,
    const float* __restrict__ Wk3, const float* __restrict__ bk3,
    float* __restrict__ ws)
{
  const int b   = blockIdx.x;
  const int tid = threadIdx.x;

  __shared__ float M[6][4][4];   // six 4x4 augmented-weight products
  __shared__ float P[NN][3];     // this batch's points

  if (tid < 96) {
    int m = tid >> 4, idx = tid & 15, r = idx >> 2, c = idx & 3;
    const float *WA = Wq, *bA = bq, *WB = Wk1, *bB = bk1;
    switch (m) {
      case 0: WA = Wq;  bA = bq;  WB = Wk1; bB = bk1; break; // A_ij  (q, k1)
      case 1: WA = Wq;  bA = bq;  WB = Wk2; bB = bk2; break; // A_ik  (q, k2)
      case 2: WA = Wq;  bA = bq;  WB = Wk3; bB = bk3; break; // A_il  (q, k3)
      case 3: WA = Wk2; bA = bk2; WB = Wk1; bB = bk1; break; // A_jkT (r=k:k2, c=j:k1)
      case 4: WA = Wk3; bA = bk3; WB = Wk1; bB = bk1; break; // A_jlT (r=l:k3, c=j:k1)
      case 5: WA = Wk2; bA = bk2; WB = Wk3; bB = bk3; break; // A_kl  (r=k:k2, c=l:k3)
    }
    float s = 0.f;
    for (int d = 0; d < DD; ++d) {
      float va = (r < 3) ? WA[r * DD + d] : bA[d];
      float vb = (c < 3) ? WB[c * DD + d] : bB[d];
      s = fmaf(va, vb, s);
    }
    M[m][r][c] = s;
  }
  if (tid < NN * 3) {
    ((float*)P)[tid] = pc[b * NN * 3 + tid];
  }
  __syncthreads();

  // scale = rsqrt(64) = 0.125; fold in -log2(e) for the exp2-based sigmoid.
  const float scale2 = -0.125f * 1.4426950408889634f;

  // 6*4096 outputs, 96 per thread; m is wave-uniform per iteration.
  for (int it = 0; it < 96; ++it) {
    int g = tid + 256 * it;
    int m = g >> 12;          // which matrix (0..5)
    int pos = g & 4095;
    int r = pos >> 6, c = pos & 63;
    float ar0 = P[r][0], ar1 = P[r][1], ar2 = P[r][2];
    float ac0 = P[c][0], ac1 = P[c][1], ac2 = P[c][2];
    const float (*Mm)[4] = M[m];
    float t0 = fmaf(Mm[0][0], ac0, fmaf(Mm[0][1], ac1, fmaf(Mm[0][2], ac2, Mm[0][3])));
    float t1 = fmaf(Mm[1][0], ac0, fmaf(Mm[1][1], ac1, fmaf(Mm[1][2], ac2, Mm[1][3])));
    float t2 = fmaf(Mm[2][0], ac0, fmaf(Mm[2][1], ac1, fmaf(Mm[2][2], ac2, Mm[2][3])));
    float t3 = fmaf(Mm[3][0], ac0, fmaf(Mm[3][1], ac1, fmaf(Mm[3][2], ac2, Mm[3][3])));
    float v = fmaf(ar0, t0, fmaf(ar1, t1, fmaf(ar2, t2, t3)));
    ws[m * MAT + b * NN * NN + pos] = v * scale2;
  }
  if (tid == 0) ws[6 * MAT + b] = 0.f;  // zero pooled[b]
}

// ---------------------------------------------------------------------------
// Main kernel: one block per (b, anchor i). lane = j; waves split k; loop l.
// Per (k,l) wave-iteration: 64 evals of sigmoid(energy)*det^2.
// Cross products (disp_k x disp_l) precomputed per block into LDS.
// ---------------------------------------------------------------------------
__global__ __launch_bounds__(256) void simplex_main(
    const float* __restrict__ pc,
    const float* __restrict__ ws_in,
    float* __restrict__ pooled)
{
  const int blk  = blockIdx.x;
  const int b    = blk >> 6;
  const int i    = blk & 63;
  const int tid  = threadIdx.x;
  const int lane = tid & 63;
  const int wave = tid >> 6;

  __shared__ float dX[NN], dY[NN], dZ[NN];         // disp (p - p_i)
  __shared__ float cX[NN * NN], cY[NN * NN], cZ[NN * NN]; // cross_kl

  const float* A_ij  = ws_in + 0 * MAT + (b * 64 + i) * 64; // [j]
  const float* A_ik  = ws_in + 1 * MAT + (b * 64 + i) * 64; // [k]
  const float* A_il  = ws_in + 2 * MAT + (b * 64 + i) * 64; // [l]
  const float* A_jkT = ws_in + 3 * MAT + b * 4096;          // [k][j]
  const float* A_jlT = ws_in + 4 * MAT + b * 4096;          // [l][j]
  const float* A_kl  = ws_in + 5 * MAT + b * 4096;          // [k][l]

  const float pix = pc[(b * 64 + i) * 3 + 0];
  const float piy = pc[(b * 64 + i) * 3 + 1];
  const float piz = pc[(b * 64 + i) * 3 + 2];

  if (tid < 64) {
    dX[tid] = pc[(b * 64 + tid) * 3 + 0] - pix;
    dY[tid] = pc[(b * 64 + tid) * 3 + 1] - piy;
    dZ[tid] = pc[(b * 64 + tid) * 3 + 2] - piz;
  }
  __syncthreads();

  for (int t2 = tid; t2 < 4096; t2 += 256) {
    int k = t2 >> 6, l = t2 & 63;
    float ax = dX[k], ay = dY[k], az = dZ[k];
    float bx = dX[l], by = dY[l], bz = dZ[l];
    cX[t2] = ay * bz - az * by;
    cY[t2] = az * bx - ax * bz;
    cZ[t2] = ax * by - ay * bx;
  }
  __syncthreads();

  const int j = lane;
  const float djx = dX[j], djy = dY[j], djz = dZ[j];
  const float eij = A_ij[j];
  float acc = 0.f;

  for (int k = wave; k < 64; k += 4) {
    // per-lane hoisted: eij + att_jk[j][k] + att_ik[k]
    const float pre = eij + A_jkT[k * 64 + j] + A_ik[k];
    const float* akl = A_kl + k * 64;
    const float* crX = cX + k * 64;
    const float* crY = cY + k * 64;
    const float* crZ = cZ + k * 64;
#pragma unroll 8
    for (int l = 0; l < 64; ++l) {
      float u = A_il[l] + akl[l];                 // uniform
      float e = pre + u + A_jlT[l * 64 + j];      // full (neg-log2e-scaled) energy
      float t = __builtin_amdgcn_exp2f(e);        // exp(-energy)
      float g = __builtin_amdgcn_rcpf(1.f + t);   // sigmoid(energy)
      float det = fmaf(djz, crZ[l], fmaf(djy, crY[l], djx * crX[l]));
      acc = fmaf(g * det, det, acc);
    }
  }

  // reduce across the 64 lanes (sums over j)
  for (int m = 32; m; m >>= 1) acc += __shfl_xor(acc, m, 64);
  if (lane == 0) {
    // /N^4 = /(64^4): converts grand sum to mean-over-anchors of agg
    atomicAdd(&pooled[b], acc * (1.f / 16777216.f));
  }
}

// ---------------------------------------------------------------------------
// Final tiny MLP: out[b] = gelu_tanh(pooled[b]*W1 + b1) @ W2 + b2
// tanh computed overflow-safe (pooled*W1 can be very large).
// ---------------------------------------------------------------------------
__global__ void simplex_final(
    const float* __restrict__ pooled,
    const float* __restrict__ W1, const float* __restrict__ b1,
    const float* __restrict__ W2, const float* __restrict__ b2,
    float* __restrict__ out)
{
  int t = threadIdx.x;
  if (t < BB) {
    float x = pooled[t];
    float o = b2[0];
    for (int c = 0; c < 32; ++c) {
      float z  = fmaf(x, W1[c], b1[c]);
      float z3 = z * z * z;
      float y  = 0.7978845608028654f * fmaf(0.044715f, z3, z);
      float ay = fabsf(y);
      // tanh(|y|) = 1 - 2/(exp(2|y|)+1); exp via exp2 (overflow -> inf -> tanh=1)
      float e  = __builtin_amdgcn_exp2f(2.8853900817779268f * ay);
      float th = 1.f - 2.f / (e + 1.f);
      th = copysignf(th, y);
      float gl = 0.5f * z * (1.f + th);
      o = fmaf(gl, W2[c], o);
    }
    out[t] = o;
  }
}

// ---------------------------------------------------------------------------
extern "C" void kernel_launch(void* const* d_in, const int* in_sizes, int n_in,
                              void* d_out, int out_size, void* d_ws, size_t ws_size,
                              hipStream_t stream) {
  (void)in_sizes; (void)n_in; (void)out_size; (void)ws_size;
  const float* pc  = (const float*)d_in[0];
  const float* Wq  = (const float*)d_in[1];
  const float* bq  = (const float*)d_in[2];
  const float* Wk1 = (const float*)d_in[3];
  const float* bk1 = (const float*)d_in[4];
  const float* Wk2 = (const float*)d_in[5];
  const float* bk2 = (const float*)d_in[6];
  const float* Wk3 = (const float*)d_in[7];
  const float* bk3 = (const float*)d_in[8];
  const float* W1  = (const float*)d_in[9];
  const float* b1  = (const float*)d_in[10];
  const float* W2  = (const float*)d_in[11];
  const float* b2  = (const float*)d_in[12];

  float* ws     = (float*)d_ws;
  float* pooled = ws + 6 * MAT;
  float* out    = (float*)d_out;

  hipLaunchKernelGGL(simplex_phase1, dim3(BB), dim3(256), 0, stream,
                     pc, Wq, bq, Wk1, bk1, Wk2, bk2, Wk3, bk3, ws);
  hipLaunchKernelGGL(simplex_main, dim3(BB * NN), dim3(256), 0, stream,
                     pc, ws, pooled);
  hipLaunchKernelGGL(simplex_final, dim3(1), dim3(64), 0, stream,
                     pooled, W1, b1, W2, b2, out);
}

// Round 2
// 285.056 us; speedup vs baseline: 1.0684x; 1.0684x over previous
//
#include <hip/hip_runtime.h>
#include <math.h>

// Problem constants: B=32 batches, N=64 points, D=64 hidden.
#define BB 32
#define NN 64
#define DD 64
constexpr int MAT = BB * NN * NN; // one (B,N,N) matrix = 131072 floats

typedef float v2f __attribute__((ext_vector_type(2)));

// ---------------------------------------------------------------------------
// Phase 1: six (B,N,N) attention matrices, scaled by -0.125*log2(e) so the
// main loop's sigmoid is rcp(1+exp2(sum)).  Matrix m==4 (att_jl^T) is stored
// as exp2() so the main loop needs NO exp2 per element (exp of sum = product
// of exps).  Grid = B*6 blocks: one (batch, matrix) per block.
// ws layout: m0 A_ij[b][i][j], m1 A_ik[b][i][k], m2 A_il[b][i][l],
//            m3 A_jkT[b][k][j], m4 EXP_jlT[b][l][j], m5 A_kl[b][k][l]
// ---------------------------------------------------------------------------
__global__ __launch_bounds__(256) void simplex_phase1(
    const float* __restrict__ pc,
    const float* __restrict__ Wq,  const float* __restrict__ bq,
    const float* __restrict__ Wk1, const float* __restrict__ bk1,
    const float* __restrict__ Wk2, const float* __restrict__ bk2,
    const float* __restrict__ Wk3, const float* __restrict__ bk3,
    float* __restrict__ ws)
{
  const int blk = blockIdx.x;
  const int m   = blk % 6;
  const int b   = blk / 6;
  const int tid = threadIdx.x;

  __shared__ float M[4][4];      // 4x4 augmented-weight product for this m
  __shared__ float P[NN][3];     // this batch's points

  if (tid < 16) {
    int r = tid >> 2, c = tid & 3;
    const float *WA = Wq, *bA = bq, *WB = Wk1, *bB = bk1;
    switch (m) {
      case 0: WA = Wq;  bA = bq;  WB = Wk1; bB = bk1; break; // A_ij
      case 1: WA = Wq;  bA = bq;  WB = Wk2; bB = bk2; break; // A_ik
      case 2: WA = Wq;  bA = bq;  WB = Wk3; bB = bk3; break; // A_il
      case 3: WA = Wk2; bA = bk2; WB = Wk1; bB = bk1; break; // A_jkT (r=k, c=j)
      case 4: WA = Wk3; bA = bk3; WB = Wk1; bB = bk1; break; // A_jlT (r=l, c=j)
      case 5: WA = Wk2; bA = bk2; WB = Wk3; bB = bk3; break; // A_kl  (r=k, c=l)
    }
    float s = 0.f;
    for (int d = 0; d < DD; ++d) {
      float va = (r < 3) ? WA[r * DD + d] : bA[d];
      float vb = (c < 3) ? WB[c * DD + d] : bB[d];
      s = fmaf(va, vb, s);
    }
    M[r][c] = s;
  }
  if (tid < NN * 3) {
    ((float*)P)[tid] = pc[b * NN * 3 + tid];
  }
  __syncthreads();

  const float scale2 = -0.125f * 1.4426950408889634f; // -scale*log2(e)

  for (int it = 0; it < 16; ++it) {
    int g = tid + 256 * it;        // 0..4095
    int r = g >> 6, c = g & 63;
    float ar0 = P[r][0], ar1 = P[r][1], ar2 = P[r][2];
    float ac0 = P[c][0], ac1 = P[c][1], ac2 = P[c][2];
    float t0 = fmaf(M[0][0], ac0, fmaf(M[0][1], ac1, fmaf(M[0][2], ac2, M[0][3])));
    float t1 = fmaf(M[1][0], ac0, fmaf(M[1][1], ac1, fmaf(M[1][2], ac2, M[1][3])));
    float t2 = fmaf(M[2][0], ac0, fmaf(M[2][1], ac1, fmaf(M[2][2], ac2, M[2][3])));
    float t3 = fmaf(M[3][0], ac0, fmaf(M[3][1], ac1, fmaf(M[3][2], ac2, M[3][3])));
    float v = fmaf(ar0, t0, fmaf(ar1, t1, fmaf(ar2, t2, t3))) * scale2;
    if (m == 4) v = __builtin_amdgcn_exp2f(v);   // wave-uniform branch
    ws[m * MAT + b * 4096 + g] = v;
  }
  if (m == 0 && tid == 0) ws[6 * MAT + b] = 0.f;  // zero pooled[b]
}

// ---------------------------------------------------------------------------
// Main kernel: one block per (b, anchor i, k-eighth). lane = j.
// sigmoid factored into 3 precomputed exp2 products -> inner loop is pure
// packed mul/fma + one rcp per TWO evals:
//   d0/x0 + d1/x1 = (d0*x1 + d1*x0) * rcp(x0*x1),  x = 1 + t >= 1.
// ---------------------------------------------------------------------------
__global__ __launch_bounds__(256, 6) void simplex_main(
    const float* __restrict__ pc,
    const float* __restrict__ ws_in,
    float* __restrict__ pooled)
{
  const int blk  = blockIdx.x;          // (b, i, q): q fastest
  const int q    = blk & 7;
  const int i    = (blk >> 3) & 63;
  const int b    = blk >> 9;
  const int k0   = q * 8;
  const int tid  = threadIdx.x;
  const int j    = tid & 63;            // lane
  const int wave = tid >> 6;

  __shared__ __align__(16) float sE[4096];                    // EXP_jlT[l][j]
  __shared__ __align__(16) float sCX[512], sCY[512], sCZ[512];// cross for 8 k's
  __shared__ __align__(16) float sR[512];                     // exp2(e_kl+e_il)
  __shared__ float dX[NN], dY[NN], dZ[NN];
  __shared__ float wsum[4];

  const float* A_ijS  = ws_in + 0 * MAT + (b * 64 + i) * 64;
  const float* A_ikS  = ws_in + 1 * MAT + (b * 64 + i) * 64;
  const float* A_ilS  = ws_in + 2 * MAT + (b * 64 + i) * 64;
  const float* A_jkTS = ws_in + 3 * MAT + b * 4096;
  const float* EXPjlT = ws_in + 4 * MAT + b * 4096;
  const float* A_klS  = ws_in + 5 * MAT + b * 4096;

  const float pix = pc[(b * 64 + i) * 3 + 0];
  const float piy = pc[(b * 64 + i) * 3 + 1];
  const float piz = pc[(b * 64 + i) * 3 + 2];

  if (tid < 64) {
    dX[tid] = pc[(b * 64 + tid) * 3 + 0] - pix;
    dY[tid] = pc[(b * 64 + tid) * 3 + 1] - piy;
    dZ[tid] = pc[(b * 64 + tid) * 3 + 2] - piz;
  }
  // stage EXP_jlT (16 KB) via float4 coalesced loads
  {
    const float4* eg = (const float4*)EXPjlT;
    float4* sg = (float4*)sE;
    sg[tid]       = eg[tid];
    sg[tid + 256] = eg[tid + 256];
    sg[tid + 512] = eg[tid + 512];
    sg[tid + 768] = eg[tid + 768];
  }
  __syncthreads();

  // cross products + r for this block's 8 k rows
  for (int t = tid; t < 512; t += 256) {
    int kl = t >> 6, l = t & 63;
    int k  = k0 + kl;
    float ax = dX[k], ay = dY[k], az = dZ[k];
    float bx = dX[l], by = dY[l], bz = dZ[l];
    sCX[t] = ay * bz - az * by;
    sCY[t] = az * bx - ax * bz;
    sCZ[t] = ax * by - ay * bx;
    sR[t]  = __builtin_amdgcn_exp2f(A_klS[k * 64 + l] + A_ilS[l]);
  }
  __syncthreads();

  const float aij = A_ijS[j];
  const float djx = dX[j], djy = dY[j], djz = dZ[j];
  const v2f djx2 = {djx, djx};
  const v2f djy2 = {djy, djy};
  const v2f djz2 = {djz, djz};
  float acc = 0.f;

  for (int kl = wave; kl < 8; kl += 4) {      // 2 k's per wave
    const int k = k0 + kl;
    const float tkv = __builtin_amdgcn_exp2f(aij + A_jkTS[k * 64 + j] + A_ikS[k]);
    const v2f tk2 = {tkv, tkv};
    const int cb = kl * 64;
#pragma unroll 2
    for (int lg = 0; lg < 64; lg += 4) {
      float4 cx4 = *(const float4*)&sCX[cb + lg];
      float4 cy4 = *(const float4*)&sCY[cb + lg];
      float4 cz4 = *(const float4*)&sCZ[cb + lg];
      float4 r4  = *(const float4*)&sR [cb + lg];
      float e0 = sE[(lg + 0) * 64 + j];
      float e1 = sE[(lg + 1) * 64 + j];
      float e2 = sE[(lg + 2) * 64 + j];
      float e3 = sE[(lg + 3) * 64 + j];
      // pair (l, l+1)
      {
        v2f r01 = {r4.x, r4.y}, e01 = {e0, e1};
        v2f t01 = tk2 * r01;
        v2f x01 = __builtin_elementwise_fma(t01, e01, (v2f){1.f, 1.f});
        v2f cxp = {cx4.x, cx4.y}, cyp = {cy4.x, cy4.y}, czp = {cz4.x, cz4.y};
        v2f det = __builtin_elementwise_fma(cxp, djx2,
                   __builtin_elementwise_fma(cyp, djy2, czp * djz2));
        v2f d2  = det * det;
        float den = x01.x * x01.y;
        float rd  = __builtin_amdgcn_rcpf(den);
        float num = fmaf(d2.x, x01.y, d2.y * x01.x);
        acc = fmaf(num, rd, acc);
      }
      // pair (l+2, l+3)
      {
        v2f r23 = {r4.z, r4.w}, e23 = {e2, e3};
        v2f t23 = tk2 * r23;
        v2f x23 = __builtin_elementwise_fma(t23, e23, (v2f){1.f, 1.f});
        v2f cxp = {cx4.z, cx4.w}, cyp = {cy4.z, cy4.w}, czp = {cz4.z, cz4.w};
        v2f det = __builtin_elementwise_fma(cxp, djx2,
                   __builtin_elementwise_fma(cyp, djy2, czp * djz2));
        v2f d2  = det * det;
        float den = x23.x * x23.y;
        float rd  = __builtin_amdgcn_rcpf(den);
        float num = fmaf(d2.x, x23.y, d2.y * x23.x);
        acc = fmaf(num, rd, acc);
      }
    }
  }

  // wave reduce (sum over j) then block reduce -> one atomic per block
  for (int s = 32; s; s >>= 1) acc += __shfl_xor(acc, s, 64);
  if (j == 0) wsum[wave] = acc;
  __syncthreads();
  if (tid == 0) {
    float blocksum = wsum[0] + wsum[1] + wsum[2] + wsum[3];
    atomicAdd(&pooled[b], blocksum * (1.f / 16777216.f)); // /N^4
  }
}

// ---------------------------------------------------------------------------
// Final tiny MLP: out[b] = gelu_tanh(pooled[b]*W1 + b1) @ W2 + b2
// ---------------------------------------------------------------------------
__global__ void simplex_final(
    const float* __restrict__ pooled,
    const float* __restrict__ W1, const float* __restrict__ b1,
    const float* __restrict__ W2, const float* __restrict__ b2,
    float* __restrict__ out)
{
  int t = threadIdx.x;
  if (t < BB) {
    float x = pooled[t];
    float o = b2[0];
    for (int c = 0; c < 32; ++c) {
      float z  = fmaf(x, W1[c], b1[c]);
      float z3 = z * z * z;
      float y  = 0.7978845608028654f * fmaf(0.044715f, z3, z);
      float ay = fabsf(y);
      float e  = __builtin_amdgcn_exp2f(2.8853900817779268f * ay);
      float th = 1.f - 2.f / (e + 1.f);
      th = copysignf(th, y);
      float gl = 0.5f * z * (1.f + th);
      o = fmaf(gl, W2[c], o);
    }
    out[t] = o;
  }
}

// ---------------------------------------------------------------------------
extern "C" void kernel_launch(void* const* d_in, const int* in_sizes, int n_in,
                              void* d_out, int out_size, void* d_ws, size_t ws_size,
                              hipStream_t stream) {
  (void)in_sizes; (void)n_in; (void)out_size; (void)ws_size;
  const float* pc  = (const float*)d_in[0];
  const float* Wq  = (const float*)d_in[1];
  const float* bq  = (const float*)d_in[2];
  const float* Wk1 = (const float*)d_in[3];
  const float* bk1 = (const float*)d_in[4];
  const float* Wk2 = (const float*)d_in[5];
  const float* bk2 = (const float*)d_in[6];
  const float* Wk3 = (const float*)d_in[7];
  const float* bk3 = (const float*)d_in[8];
  const float* W1  = (const float*)d_in[9];
  const float* b1  = (const float*)d_in[10];
  const float* W2  = (const float*)d_in[11];
  const float* b2  = (const float*)d_in[12];

  float* ws     = (float*)d_ws;
  float* pooled = ws + 6 * MAT;
  float* out    = (float*)d_out;

  hipLaunchKernelGGL(simplex_phase1, dim3(BB * 6), dim3(256), 0, stream,
                     pc, Wq, bq, Wk1, bk1, Wk2, bk2, Wk3, bk3, ws);
  hipLaunchKernelGGL(simplex_main, dim3(BB * NN * 8), dim3(256), 0, stream,
                     pc, ws, pooled);
  hipLaunchKernelGGL(simplex_final, dim3(1), dim3(64), 0, stream,
                     pooled, W1, b1, W2, b2, out);
}

// Round 3
// 190.437 us; speedup vs baseline: 1.5992x; 1.4969x over previous
//
#include <hip/hip_runtime.h>
#include <math.h>

// Problem constants: B=32 batches, N=64 points, D=64 hidden.
#define BB 32
#define NN 64
#define DD 64
constexpr int MAT = BB * NN * NN;           // one (B,N,N) matrix = 131072 floats
constexpr int DJ_OFF = 6 * MAT;             // dj-pack: [b][i][jp][8] floats
constexpr int DJ_PER_B = 64 * 32 * 8;       // 16384 floats per batch
constexpr int POOLED_OFF = DJ_OFF + BB * DJ_PER_B;

typedef float v2f __attribute__((ext_vector_type(2)));

// ---------------------------------------------------------------------------
// Phase 1 (grid B*7): blocks m=0..5 compute the six bilinear attention
// matrices (scaled by -0.125*log2e); m4 = E_jl stored as exp2, PAIR-
// INTERLEAVED over j: [jp][l][2]; m5 = R_kl stored as exp2. Block m=6 builds
// the per-(i, j-pair) displacement pack {x0,x1,y0,y1,z0,z1,0,0} used via
// s_load in the main kernel.
// Key identity: q_i.k_j = aug(p_i)^T (W_A aug W_B aug^T) aug(p_j), 4x4 form.
// ---------------------------------------------------------------------------
__global__ __launch_bounds__(256) void simplex_phase1(
    const float* __restrict__ pc,
    const float* __restrict__ Wq,  const float* __restrict__ bq,
    const float* __restrict__ Wk1, const float* __restrict__ bk1,
    const float* __restrict__ Wk2, const float* __restrict__ bk2,
    const float* __restrict__ Wk3, const float* __restrict__ bk3,
    float* __restrict__ ws)
{
  const int blk = blockIdx.x;
  const int m   = blk % 7;
  const int b   = blk / 7;
  const int tid = threadIdx.x;

  __shared__ float M[4][4];
  __shared__ float P[NN][3];

  if (m < 6 && tid < 16) {
    int r = tid >> 2, c = tid & 3;
    const float *WA = Wq, *bA = bq, *WB = Wk1, *bB = bk1;
    switch (m) {
      case 0: WA = Wq;  bA = bq;  WB = Wk1; bB = bk1; break; // A_ij  (q,  k1)
      case 1: WA = Wq;  bA = bq;  WB = Wk2; bB = bk2; break; // A_ik  (q,  k2)
      case 2: WA = Wq;  bA = bq;  WB = Wk3; bB = bk3; break; // A_il  (q,  k3)
      case 3: WA = Wk2; bA = bk2; WB = Wk1; bB = bk1; break; // A_jkT (r=k, c=j)
      case 4: WA = Wk1; bA = bk1; WB = Wk3; bB = bk3; break; // E_jl  (r=j, c=l)
      case 5: WA = Wk2; bA = bk2; WB = Wk3; bB = bk3; break; // R_kl  (r=k, c=l)
    }
    float s = 0.f;
    for (int d = 0; d < DD; ++d) {
      float va = (r < 3) ? WA[r * DD + d] : bA[d];
      float vb = (c < 3) ? WB[c * DD + d] : bB[d];
      s = fmaf(va, vb, s);
    }
    M[r][c] = s;
  }
  if (tid < NN * 3) {
    ((float*)P)[tid] = pc[b * NN * 3 + tid];
  }
  __syncthreads();

  if (m == 6) {
    // dj-pack: [i][jp][8] = {x(2j),x(2j+1), y.., y.., z.., z.., 0, 0}
    for (int idx = tid; idx < DJ_PER_B; idx += 256) {
      int word = idx & 7;
      int jp   = (idx >> 3) & 31;
      int i    = idx >> 8;
      float v = 0.f;
      if (word < 6) {
        int axis = word >> 1;
        int j    = jp * 2 + (word & 1);
        v = P[j][axis] - P[i][axis];
      }
      ws[DJ_OFF + b * DJ_PER_B + idx] = v;
    }
    return;
  }

  const float scale2 = -0.125f * 1.4426950408889634f; // -scale*log2(e)

  for (int it = 0; it < 16; ++it) {
    int g = tid + 256 * it;        // 0..4095
    int r = g >> 6, c = g & 63;
    float ar0 = P[r][0], ar1 = P[r][1], ar2 = P[r][2];
    float ac0 = P[c][0], ac1 = P[c][1], ac2 = P[c][2];
    float t0 = fmaf(M[0][0], ac0, fmaf(M[0][1], ac1, fmaf(M[0][2], ac2, M[0][3])));
    float t1 = fmaf(M[1][0], ac0, fmaf(M[1][1], ac1, fmaf(M[1][2], ac2, M[1][3])));
    float t2 = fmaf(M[2][0], ac0, fmaf(M[2][1], ac1, fmaf(M[2][2], ac2, M[2][3])));
    float t3 = fmaf(M[3][0], ac0, fmaf(M[3][1], ac1, fmaf(M[3][2], ac2, M[3][3])));
    float v = fmaf(ar0, t0, fmaf(ar1, t1, fmaf(ar2, t2, t3))) * scale2;
    if (m == 4) {
      // exp2, pair-interleaved over j (=r): [jp][l][2]
      float e = __builtin_amdgcn_exp2f(v);
      ws[4 * MAT + b * 4096 + ((r >> 1) << 7) + (c << 1) + (r & 1)] = e;
    } else if (m == 5) {
      ws[5 * MAT + b * 4096 + g] = __builtin_amdgcn_exp2f(v);
    } else {
      ws[m * MAT + b * 4096 + g] = v;
    }
  }
  if (m == 0 && tid == 0) ws[POOLED_OFF + b] = 0.f;  // zero pooled[b]
}

// ---------------------------------------------------------------------------
// Main kernel: one block per (b, anchor i). LANE = l; j runs as PAIRS in the
// inner loop; waves split k (2-k unroll). Cross products live in per-lane
// registers; per-j uniform data comes from SMEM (s_load of dj-pack); only
// E (per-lane b64) and T (broadcast b64) touch the DS pipe in the hot loop.
//   x = 1 + T_jk * E_jl * (R_kl * w_il)   ;  gate = 1/x
//   det = d_j . (d_k x d_l)               ;  acc += gate*det^2 (paired rcp)
// ---------------------------------------------------------------------------
__global__ __launch_bounds__(256, 8) void simplex_main(
    const float* __restrict__ pc,
    const float* __restrict__ ws_in,
    float* __restrict__ pooled)
{
  const int b    = blockIdx.x >> 6;
  const int i    = blockIdx.x & 63;
  const int tid  = threadIdx.x;
  const int lane = tid & 63;
  const int wu   = __builtin_amdgcn_readfirstlane(tid >> 6);

  __shared__ __align__(16) float sE[4096];   // E pair-interleaved [jp][l][2]
  __shared__ float sT[512];                  // per-wave T rows: [w][2][64]
  __shared__ float dX[NN], dY[NN], dZ[NN];
  __shared__ float wsum[4];

  const float* m0  = ws_in + 0 * MAT + (b * 64 + i) * 64; // A_ij[j]
  const float* m1  = ws_in + 1 * MAT + (b * 64 + i) * 64; // A_ik[k]
  const float* m2  = ws_in + 2 * MAT + (b * 64 + i) * 64; // A_il[l]
  const float* m3  = ws_in + 3 * MAT + b * 4096;          // A_jkT[k][j]
  const float* m4  = ws_in + 4 * MAT + b * 4096;          // E interleaved
  const float* m5  = ws_in + 5 * MAT + b * 4096;          // R_kl[k][l]
  const float* djp = ws_in + DJ_OFF + b * DJ_PER_B + i * 256; // [jp][8]

  // ---- stage E (16 KB) and displacements ----
  {
    const float4* src = (const float4*)m4;
    float4* dst = (float4*)sE;
    dst[tid]       = src[tid];
    dst[tid + 256] = src[tid + 256];
    dst[tid + 512] = src[tid + 512];
    dst[tid + 768] = src[tid + 768];
  }
  if (tid < 64) {
    const float pix = pc[(b * 64 + i) * 3 + 0];
    const float piy = pc[(b * 64 + i) * 3 + 1];
    const float piz = pc[(b * 64 + i) * 3 + 2];
    dX[tid] = pc[(b * 64 + tid) * 3 + 0] - pix;
    dY[tid] = pc[(b * 64 + tid) * 3 + 1] - piy;
    dZ[tid] = pc[(b * 64 + tid) * 3 + 2] - piz;
  }
  __syncthreads();

  const float dlx = dX[lane], dly = dY[lane], dlz = dZ[lane];
  const float wl  = __builtin_amdgcn_exp2f(m2[lane]); // exp2(A_il[l]) per-lane
  const float aij = m0[lane];                          // lane also plays j here
  float* sTw = sT + wu * 128;
  float acc = 0.f;

  for (int kk0 = 2 * wu; kk0 < 64; kk0 += 8) {
    const int kk = __builtin_amdgcn_readfirstlane(kk0);
    v2f cx2[2], cy2[2], cz2[2], mm2[2];
#pragma unroll
    for (int t = 0; t < 2; ++t) {
      const int k = kk + t;
      const float dkx = dX[k], dky = dY[k], dkz = dZ[k];  // broadcast
      const float cx = dky * dlz - dkz * dly;             // d_k x d_l (per-lane)
      const float cy = dkz * dlx - dkx * dlz;
      const float cz = dkx * dly - dky * dlx;
      cx2[t] = (v2f){cx, cx};
      cy2[t] = (v2f){cy, cy};
      cz2[t] = (v2f){cz, cz};
      const float mv = m5[k * 64 + lane] * wl;            // R_kl * w_il
      mm2[t] = (v2f){mv, mv};
      // T row for this k (lane plays j): exp2(a_ij + a_jk + a_ik)
      const float Tv = __builtin_amdgcn_exp2f(aij + m3[k * 64 + lane] + m1[k]);
      sTw[t * 64 + lane] = Tv;
    }
    // same-wave LDS write->read: compiler inserts lgkmcnt wait; no barrier.
#pragma unroll 2
    for (int jp = 0; jp < 32; ++jp) {
      const v2f xx = *(const v2f*)(djp + jp * 8 + 0);  // uniform -> s_load
      const v2f yy = *(const v2f*)(djp + jp * 8 + 2);
      const v2f zz = *(const v2f*)(djp + jp * 8 + 4);
      const v2f E01 = *(const v2f*)&sE[jp * 128 + lane * 2]; // per-lane b64
      v2f Tt[2];
      Tt[0] = *(const v2f*)&sTw[2 * jp];        // broadcast b64
      Tt[1] = *(const v2f*)&sTw[64 + 2 * jp];
#pragma unroll
      for (int t = 0; t < 2; ++t) {
        v2f e01 = E01 * mm2[t];
        v2f x01 = __builtin_elementwise_fma(Tt[t], e01, (v2f){1.f, 1.f});
        v2f det = __builtin_elementwise_fma(xx, cx2[t],
                    __builtin_elementwise_fma(yy, cy2[t], zz * cz2[t]));
        v2f d2  = det * det;
        float den = x01.x * x01.y;
        float rd  = __builtin_amdgcn_rcpf(den);
        float num = fmaf(d2.x, x01.y, d2.y * x01.x);
        acc = fmaf(num, rd, acc);
      }
    }
  }

  // reduce: lanes sum over l; waves sum over their k slices
  for (int s = 32; s; s >>= 1) acc += __shfl_xor(acc, s, 64);
  if (lane == 0) wsum[wu] = acc;
  __syncthreads();
  if (tid == 0) {
    float blocksum = wsum[0] + wsum[1] + wsum[2] + wsum[3];
    atomicAdd(&pooled[b], blocksum * (1.f / 16777216.f)); // / N^4
  }
}

// ---------------------------------------------------------------------------
// Final tiny MLP: out[b] = gelu_tanh(pooled[b]*W1 + b1) @ W2 + b2
// ---------------------------------------------------------------------------
__global__ void simplex_final(
    const float* __restrict__ pooled,
    const float* __restrict__ W1, const float* __restrict__ b1,
    const float* __restrict__ W2, const float* __restrict__ b2,
    float* __restrict__ out)
{
  int t = threadIdx.x;
  if (t < BB) {
    float x = pooled[t];
    float o = b2[0];
    for (int c = 0; c < 32; ++c) {
      float z  = fmaf(x, W1[c], b1[c]);
      float z3 = z * z * z;
      float y  = 0.7978845608028654f * fmaf(0.044715f, z3, z);
      float ay = fabsf(y);
      float e  = __builtin_amdgcn_exp2f(2.8853900817779268f * ay);
      float th = 1.f - 2.f / (e + 1.f);
      th = copysignf(th, y);
      float gl = 0.5f * z * (1.f + th);
      o = fmaf(gl, W2[c], o);
    }
    out[t] = o;
  }
}

// ---------------------------------------------------------------------------
extern "C" void kernel_launch(void* const* d_in, const int* in_sizes, int n_in,
                              void* d_out, int out_size, void* d_ws, size_t ws_size,
                              hipStream_t stream) {
  (void)in_sizes; (void)n_in; (void)out_size; (void)ws_size;
  const float* pc  = (const float*)d_in[0];
  const float* Wq  = (const float*)d_in[1];
  const float* bq  = (const float*)d_in[2];
  const float* Wk1 = (const float*)d_in[3];
  const float* bk1 = (const float*)d_in[4];
  const float* Wk2 = (const float*)d_in[5];
  const float* bk2 = (const float*)d_in[6];
  const float* Wk3 = (const float*)d_in[7];
  const float* bk3 = (const float*)d_in[8];
  const float* W1  = (const float*)d_in[9];
  const float* b1  = (const float*)d_in[10];
  const float* W2  = (const float*)d_in[11];
  const float* b2  = (const float*)d_in[12];

  float* ws     = (float*)d_ws;
  float* pooled = ws + POOLED_OFF;
  float* out    = (float*)d_out;

  hipLaunchKernelGGL(simplex_phase1, dim3(BB * 7), dim3(256), 0, stream,
                     pc, Wq, bq, Wk1, bk1, Wk2, bk2, Wk3, bk3, ws);
  hipLaunchKernelGGL(simplex_main, dim3(BB * NN), dim3(256), 0, stream,
                     pc, ws, pooled);
  hipLaunchKernelGGL(simplex_final, dim3(1), dim3(64), 0, stream,
                     pooled, W1, b1, W2, b2, out);
}